// Round 7
// baseline (708.658 us; speedup 1.0000x reference)
//
#include <hip/hip_runtime.h>
#include <hip/hip_bf16.h>

typedef __bf16 bf16_t;
typedef __bf16 bf16x4 __attribute__((ext_vector_type(4)));
typedef __bf16 bf16x8 __attribute__((ext_vector_type(8)));
typedef float  f32x4  __attribute__((ext_vector_type(4)));
typedef int    i32x2  __attribute__((ext_vector_type(2)));
typedef int    i32x4  __attribute__((ext_vector_type(4)));

#define N_NODES 100000
#define F_INC   128
#define HDIM    256
#define NEDGE   1000000
#define ELL_CAP 48
#define GATHER_BLKS (N_NODES / 4)             // 25000
#define GEMM_BLKS   ((N_NODES / 16 + 3) / 4)  // 1563
#define FILL_BLKS   ((NEDGE + 255) / 256)     // 3907

// ---------------- zero a count array ----------------
__global__ void zero_cnt(int* __restrict__ cnt, int n) {
    int i = blockIdx.x * 256 + threadIdx.x;
    if (i < n) cnt[i] = 0;
}

// ---------------- detect edge-index storage: int32 (flag=0) vs int64 (flag=1) --------
__global__ void detect_kernel(const int* __restrict__ eit, const int* __restrict__ eil,
                              int* __restrict__ flags) {
    int lane = threadIdx.x & 63;
    const int* p = (threadIdx.x < 64) ? eit : eil;
    int s = (p[2 * lane + 1] != 0) ? 1 : 0;
    #pragma unroll
    for (int off = 1; off < 64; off <<= 1) s += __shfl_xor(s, off, 64);
    if (lane == 0) flags[(threadIdx.x < 64) ? 0 : 1] = (s == 0) ? 1 : 0;
}

// ---------------- pre-pack W1 into bf16 MFMA B-fragment order; zero sentinel rows ------
__global__ void wprep_kernel(const float* __restrict__ W1, bf16_t* __restrict__ wlay,
                             bf16_t* __restrict__ xw, bf16_t* __restrict__ zb) {
    int t = blockIdx.x * 256 + threadIdx.x;        // 0..32767
    if (blockIdx.x == 0) {
        xw[(size_t)N_NODES * HDIM + threadIdx.x] = (bf16_t)0.f;  // sentinel row
        zb[(size_t)N_NODES * HDIM + threadIdx.x] = (bf16_t)0.f;  // sentinel row
    }
    int j = t & 7, lane = (t >> 3) & 63, kk = (t >> 9) & 3, nt = t >> 11;
    int m = lane & 15, q = lane >> 4;
    int k = kk * 32 + q * 8 + j;
    int n = nt * 16 + m;
    wlay[t] = (bf16_t)W1[k * HDIM + n];
}

// ---------------- gemm body: 16 rows x 256 cols per wave, row-norm fused ----------------
__device__ __forceinline__ void gemm_body(int w, int lane, const float* __restrict__ x,
                                          const bf16_t* __restrict__ wlay,
                                          bf16_t* __restrict__ xw) {
    if (w >= N_NODES / 16) return;                 // 6250 waves exactly
    int m = lane & 15, q = lane >> 4;
    int r0 = w * 16;
    int row = r0 + m;
    const float4* xr = (const float4*)(x + (size_t)row * F_INC);
    float4 u[8];
    #pragma unroll
    for (int kk = 0; kk < 4; kk++) {
        u[2 * kk]     = xr[kk * 8 + q * 2];
        u[2 * kk + 1] = xr[kk * 8 + q * 2 + 1];
    }
    float ss = 0.f;
    #pragma unroll
    for (int j = 0; j < 8; j++)
        ss += u[j].x * u[j].x + u[j].y * u[j].y + u[j].z * u[j].z + u[j].w * u[j].w;
    ss += __shfl_xor(ss, 16, 64);
    ss += __shfl_xor(ss, 32, 64);
    float rv = 1.0f / fmaxf(sqrtf(ss), 1e-12f);
    bf16x8 a[4];
    #pragma unroll
    for (int kk = 0; kk < 4; kk++) {
        float4 p0 = u[2 * kk], p1 = u[2 * kk + 1];
        a[kk][0] = (bf16_t)(p0.x * rv); a[kk][1] = (bf16_t)(p0.y * rv);
        a[kk][2] = (bf16_t)(p0.z * rv); a[kk][3] = (bf16_t)(p0.w * rv);
        a[kk][4] = (bf16_t)(p1.x * rv); a[kk][5] = (bf16_t)(p1.y * rv);
        a[kk][6] = (bf16_t)(p1.z * rv); a[kk][7] = (bf16_t)(p1.w * rv);
    }
    const bf16x8* wl = (const bf16x8*)wlay;
    #pragma unroll
    for (int nt = 0; nt < 16; nt++) {
        f32x4 c = {0.f, 0.f, 0.f, 0.f};
        c = __builtin_amdgcn_mfma_f32_16x16x32_bf16(a[0], wl[(nt * 4 + 0) * 64 + lane], c, 0, 0, 0);
        c = __builtin_amdgcn_mfma_f32_16x16x32_bf16(a[1], wl[(nt * 4 + 1) * 64 + lane], c, 0, 0, 0);
        c = __builtin_amdgcn_mfma_f32_16x16x32_bf16(a[2], wl[(nt * 4 + 2) * 64 + lane], c, 0, 0, 0);
        c = __builtin_amdgcn_mfma_f32_16x16x32_bf16(a[3], wl[(nt * 4 + 3) * 64 + lane], c, 0, 0, 0);
        #pragma unroll
        for (int i = 0; i < 4; i++) {
            xw[(size_t)(r0 + q * 4 + i) * HDIM + nt * 16 + m] = (bf16_t)c[i];
        }
    }
}

// ---------------- ELL builders: paired (src,eid) for top; src-only for last -------------
__device__ __forceinline__ void fill2_body(int e, const int* __restrict__ ei,
                                           const int* __restrict__ flag,
                                           int* __restrict__ cnt, int* __restrict__ ell2) {
    if (e >= NEDGE) return;
    int f = *flag;
    int src = ei[e << f];
    int dst = ei[(NEDGE + e) << f];
    int slot = atomicAdd(&cnt[dst], 1);
    if (slot < ELL_CAP) {
        int2 pr; pr.x = src; pr.y = e;
        ((int2*)ell2)[(size_t)dst * ELL_CAP + slot] = pr;
    }
}

__device__ __forceinline__ void fill_body(int e, const int* __restrict__ ei,
                                          const int* __restrict__ flag,
                                          int* __restrict__ cnt, int* __restrict__ ell) {
    if (e >= NEDGE) return;
    int f = *flag;
    int src = ei[e << f];
    int dst = ei[(NEDGE + e) << f];
    int slot = atomicAdd(&cnt[dst], 1);
    if (slot < ELL_CAP) ell[dst * ELL_CAP + slot] = src;
}

// ---------------- FUSED-A: gemm + fill2(top) + fill(last), all independent --------------
__global__ __launch_bounds__(256) void gemm_fill_kernel(const float* __restrict__ x,
                                                        const bf16_t* __restrict__ wlay,
                                                        bf16_t* __restrict__ xw,
                                                        const int* __restrict__ ei_t,
                                                        const int* __restrict__ flags,
                                                        int* __restrict__ cnt_t,
                                                        int* __restrict__ ell2t,
                                                        const int* __restrict__ ei_l,
                                                        int* __restrict__ cnt_l,
                                                        int* __restrict__ ell_l) {
    if (blockIdx.x < GEMM_BLKS) {
        gemm_body(blockIdx.x * 4 + (threadIdx.x >> 6), threadIdx.x & 63, x, wlay, xw);
    } else if (blockIdx.x < GEMM_BLKS + FILL_BLKS) {
        fill2_body((blockIdx.x - GEMM_BLKS) * 256 + threadIdx.x, ei_t, flags, cnt_t, ell2t);
    } else {
        fill_body((blockIdx.x - GEMM_BLKS - FILL_BLKS) * 256 + threadIdx.x, ei_l, flags + 1,
                  cnt_l, ell_l);
    }
}

// ---------------- dinv for both graphs; pad top ELL (paired) to x8, last to x4 ----------
__global__ void dinvpad_both(const int* __restrict__ cnt_t, const int* __restrict__ cnt_l,
                             float* __restrict__ dinv_t, float* __restrict__ dinv_l,
                             int* __restrict__ ell2t, int* __restrict__ ell_l) {
    int i = blockIdx.x * 256 + threadIdx.x;
    if (i >= N_NODES) {
        if (i == N_NODES) { dinv_t[N_NODES] = 0.f; dinv_l[N_NODES] = 0.f; }
        return;
    }
    int ct = cnt_t[i];
    dinv_t[i] = rsqrtf((float)ct + 1.0f);
    int dt = (ct > ELL_CAP) ? ELL_CAP : ct;
    int r8 = (dt + 7) & ~7;                        // aedge consumes 8 slots/iter
    int2 pr; pr.x = N_NODES; pr.y = -1;
    for (int s = dt; s < r8; s++) ((int2*)ell2t)[(size_t)i * ELL_CAP + s] = pr;
    int cl = cnt_l[i];
    dinv_l[i] = rsqrtf((float)cl + 1.0f);
    int dl = (cl > ELL_CAP) ? ELL_CAP : cl;
    int r4 = (dl + 3) & ~3;
    for (int s = dl; s < r4; s++) ell_l[(size_t)i * ELL_CAP + s] = N_NODES;
}

// ---------------- DUAL gather conv: both graphs for node i in one pass ------------------
// 8 independent row loads per iteration (4 top + 4 last, sentinel-predicated)
__global__ __launch_bounds__(256) void dual_gather_kernel(const int* __restrict__ ell2t,
                                                          const int* __restrict__ cnt_t,
                                                          const float* __restrict__ dinv_t,
                                                          const int* __restrict__ ell_l,
                                                          const int* __restrict__ cnt_l,
                                                          const float* __restrict__ dinv_l,
                                                          const bf16_t* __restrict__ xw,
                                                          const float* __restrict__ b1,
                                                          float* __restrict__ out0,
                                                          float* __restrict__ out1,
                                                          bf16_t* __restrict__ zb) {
    int i = blockIdx.x * 4 + (threadIdx.x >> 6);
    int lane = threadIdx.x & 63;
    const bf16x4* xws = (const bf16x4*)xw;         // row r at index r*64 + lane
    bf16x4 sv = xws[(size_t)i * 64 + lane];
    float dt = dinv_t[i], dl = dinv_l[i];
    float at0 = dt * (float)sv.x, at1 = dt * (float)sv.y;
    float at2 = dt * (float)sv.z, at3 = dt * (float)sv.w;
    float al0 = dl * (float)sv.x, al1 = dl * (float)sv.y;
    float al2 = dl * (float)sv.z, al3 = dl * (float)sv.w;
    int degt = cnt_t[i]; if (degt > ELL_CAP) degt = ELL_CAP;
    int degl = cnt_l[i]; if (degl > ELL_CAP) degl = ELL_CAP;
    int nt4 = (degt + 3) >> 2, nl4 = (degl + 3) >> 2;
    int nit = nt4 > nl4 ? nt4 : nl4;
    const i32x4* e8  = (const i32x4*)ell2t + (size_t)i * (ELL_CAP / 2);
    const i32x4* el4 = (const i32x4*)(ell_l + (size_t)i * ELL_CAP);
    for (int b = 0; b < nit; b++) {
        bool ht = b < nt4, hl = b < nl4;
        int bt = ht ? 2 * b : 0;
        int bl = hl ? b : 0;
        i32x4 ta = __builtin_nontemporal_load(e8 + bt);        // read-once index stream
        i32x4 tb = __builtin_nontemporal_load(e8 + bt + 1);
        i32x4 la = __builtin_nontemporal_load(el4 + bl);
        int t0 = ht ? ta[0] : N_NODES, t1 = ht ? ta[2] : N_NODES;
        int t2 = ht ? tb[0] : N_NODES, t3 = ht ? tb[2] : N_NODES;
        int l0 = hl ? la[0] : N_NODES, l1 = hl ? la[1] : N_NODES;
        int l2 = hl ? la[2] : N_NODES, l3 = hl ? la[3] : N_NODES;
        // issue all 8 row loads before the FMAs (deep MLP)
        bf16x4 vt0 = xws[(size_t)t0 * 64 + lane];
        bf16x4 vt1 = xws[(size_t)t1 * 64 + lane];
        bf16x4 vt2 = xws[(size_t)t2 * 64 + lane];
        bf16x4 vt3 = xws[(size_t)t3 * 64 + lane];
        bf16x4 vl0 = xws[(size_t)l0 * 64 + lane];
        bf16x4 vl1 = xws[(size_t)l1 * 64 + lane];
        bf16x4 vl2 = xws[(size_t)l2 * 64 + lane];
        bf16x4 vl3 = xws[(size_t)l3 * 64 + lane];
        float w0 = dinv_t[t0], w1 = dinv_t[t1], w2 = dinv_t[t2], w3 = dinv_t[t3];
        float u0 = dinv_l[l0], u1 = dinv_l[l1], u2 = dinv_l[l2], u3 = dinv_l[l3];
        at0 += w0 * (float)vt0.x + w1 * (float)vt1.x + w2 * (float)vt2.x + w3 * (float)vt3.x;
        at1 += w0 * (float)vt0.y + w1 * (float)vt1.y + w2 * (float)vt2.y + w3 * (float)vt3.y;
        at2 += w0 * (float)vt0.z + w1 * (float)vt1.z + w2 * (float)vt2.z + w3 * (float)vt3.z;
        at3 += w0 * (float)vt0.w + w1 * (float)vt1.w + w2 * (float)vt2.w + w3 * (float)vt3.w;
        al0 += u0 * (float)vl0.x + u1 * (float)vl1.x + u2 * (float)vl2.x + u3 * (float)vl3.x;
        al1 += u0 * (float)vl0.y + u1 * (float)vl1.y + u2 * (float)vl2.y + u3 * (float)vl3.y;
        al2 += u0 * (float)vl0.z + u1 * (float)vl1.z + u2 * (float)vl2.z + u3 * (float)vl3.z;
        al3 += u0 * (float)vl0.w + u1 * (float)vl1.w + u2 * (float)vl2.w + u3 * (float)vl3.w;
    }
    float4 bv = ((const float4*)b1)[lane];
    f32x4 o0, o1;
    o0[0] = dt * at0 + bv.x; o0[1] = dt * at1 + bv.y;
    o0[2] = dt * at2 + bv.z; o0[3] = dt * at3 + bv.w;
    o1[0] = dl * al0 + bv.x; o1[1] = dl * al1 + bv.y;
    o1[2] = dl * al2 + bv.z; o1[3] = dl * al3 + bv.w;
    __builtin_nontemporal_store(o0, (f32x4*)out0 + (size_t)i * 64 + lane);
    __builtin_nontemporal_store(o1, (f32x4*)out1 + (size_t)i * 64 + lane);
    bf16x4 zo;
    zo.x = (bf16_t)o0[0]; zo.y = (bf16_t)o0[1]; zo.z = (bf16_t)o0[2]; zo.w = (bf16_t)o0[3];
    ((bf16x4*)zb)[(size_t)i * 64 + lane] = zo;     // re-read by aedge: cached
}

// ---------------- aedge (dst-major, unroll 2): dst row loaded once per node -------------
// wave = one dst node; 4x 16-lane groups, each handles 2 edge slots per iteration
__global__ __launch_bounds__(256) void aedge_kernel(const int* __restrict__ ell2,
                                                    const int* __restrict__ cnt,
                                                    const bf16_t* __restrict__ zb,
                                                    float* __restrict__ aedge) {
    int i = blockIdx.x * 4 + (threadIdx.x >> 6);
    int lane = threadIdx.x & 63;
    int sub = lane & 15, g = lane >> 4;
    const bf16x8* z8 = (const bf16x8*)zb;          // row r: 32 bf16x8 at r*32
    bf16x8 d0 = z8[(size_t)i * 32 + sub * 2];      // dst row: once per node
    bf16x8 d1 = z8[(size_t)i * 32 + sub * 2 + 1];
    int deg = cnt[i];
    if (deg > ELL_CAP) deg = ELL_CAP;
    int nit = (deg + 7) >> 3;                      // ELL padded to mult of 8
    const i32x2* pr = (const i32x2*)ell2 + (size_t)i * ELL_CAP;
    for (int b = 0; b < nit; b++) {
        i32x2 pA = __builtin_nontemporal_load(pr + b * 8 + g);
        i32x2 pB = __builtin_nontemporal_load(pr + b * 8 + 4 + g);
        int sA = pA[0], sB = pB[0];
        bf16x8 a0 = z8[(size_t)sA * 32 + sub * 2];
        bf16x8 a1 = z8[(size_t)sA * 32 + sub * 2 + 1];
        bf16x8 c0 = z8[(size_t)sB * 32 + sub * 2];
        bf16x8 c1 = z8[(size_t)sB * 32 + sub * 2 + 1];
        float p = 0.f, q = 0.f;
        #pragma unroll
        for (int j = 0; j < 8; j++) {
            p += (float)a0[j] * (float)d0[j] + (float)a1[j] * (float)d1[j];
            q += (float)c0[j] * (float)d0[j] + (float)c1[j] * (float)d1[j];
        }
        #pragma unroll
        for (int off = 1; off < 16; off <<= 1) {
            p += __shfl_xor(p, off, 64);
            q += __shfl_xor(q, off, 64);
        }
        if (sub == 0) {
            if (pA[1] >= 0)
                __builtin_nontemporal_store(1.0f / (1.0f + __expf(-p)), &aedge[pA[1]]);
            if (pB[1] >= 0)
                __builtin_nontemporal_store(1.0f / (1.0f + __expf(-q)), &aedge[pB[1]]);
        }
    }
}

extern "C" void kernel_launch(void* const* d_in, const int* in_sizes, int n_in,
                              void* d_out, int out_size, void* d_ws, size_t ws_size,
                              hipStream_t stream) {
    const float* x       = (const float*)d_in[0];
    const int*   ei_top  = (const int*)d_in[1];
    const int*   ei_last = (const int*)d_in[2];
    const float* W1      = (const float*)d_in[3];
    const float* b1      = (const float*)d_in[4];
    float* out = (float*)d_out;

    char* ws = (char*)d_ws;
    bf16_t* xw     = (bf16_t*)(ws);                  //  51,200,512 B (+sentinel row)
    bf16_t* zb     = (bf16_t*)(ws + 51201024);       //  51,200,512 B (+sentinel row)
    int*    ell2t  = (int*)  (ws + 102402048);       //  38,400,000 B (src,eid pairs, top)
    int*    ell_l  = (int*)  (ws + 140802048);       //  19,200,000 B (src only, last)
    float*  dinv_t = (float*)(ws + 160002048);       //     400,064 B (N+1 floats)
    float*  dinv_l = (float*)(ws + 160402112);       //     400,064 B
    int*    cnt_t  = (int*)  (ws + 160802176);       //     400,000 B
    int*    cnt_l  = (int*)  (ws + 161202176);       //     400,000 B (contiguous w/ cnt_t)
    bf16_t* wlay   = (bf16_t*)(ws + 161602176);      //      65,536 B
    int*    flags  = (int*)  (ws + 161667712);       //          64 B -> 161,667,776 total

    zero_cnt<<<(2 * N_NODES + 255) / 256, 256, 0, stream>>>(cnt_t, 2 * N_NODES);
    detect_kernel<<<1, 128, 0, stream>>>(ei_top, ei_last, flags);
    wprep_kernel<<<128, 256, 0, stream>>>(W1, wlay, xw, zb);
    // gemm + both edge-list fills (all independent)
    gemm_fill_kernel<<<GEMM_BLKS + 2 * FILL_BLKS, 256, 0, stream>>>(
        x, wlay, xw, ei_top, flags, cnt_t, ell2t, ei_last, cnt_l, ell_l);
    dinvpad_both<<<(N_NODES + 256) / 256 + 1, 256, 0, stream>>>(cnt_t, cnt_l,
                                                                dinv_t, dinv_l, ell2t, ell_l);
    // both convs in one pass: xw is the only hot random-read array
    dual_gather_kernel<<<GATHER_BLKS, 256, 0, stream>>>(
        ell2t, cnt_t, dinv_t, ell_l, cnt_l, dinv_l, xw, b1,
        out, out + (size_t)N_NODES * HDIM, zb);
    // aedge alone: zb owns L3
    aedge_kernel<<<GATHER_BLKS, 256, 0, stream>>>(ell2t, cnt_t, zb,
                                                  out + (size_t)2 * N_NODES * HDIM);
}

// Round 8
// 677.617 us; speedup vs baseline: 1.0458x; 1.0458x over previous
//
#include <hip/hip_runtime.h>
#include <hip/hip_bf16.h>

typedef __bf16 bf16_t;
typedef __bf16 bf16x4 __attribute__((ext_vector_type(4)));
typedef __bf16 bf16x8 __attribute__((ext_vector_type(8)));
typedef float  f32x4  __attribute__((ext_vector_type(4)));
typedef int    i32x2  __attribute__((ext_vector_type(2)));
typedef int    i32x4  __attribute__((ext_vector_type(4)));

#define N_NODES 100000
#define F_INC   128
#define HDIM    256
#define NEDGE   1000000
#define ELL_CAP 48
#define GATHER_BLKS (N_NODES / 4)             // 25000
#define GEMM_BLKS   ((N_NODES / 16 + 3) / 4)  // 1563
#define FILL_BLKS   ((NEDGE + 255) / 256)     // 3907
#define ZERO_BLKS   ((2 * N_NODES + 255) / 256) // 782

// ---------------- PREP: zero counters + detect int32/64 + pre-pack W1 -------------------
// blocks [0,782): zero cnt_t/cnt_l; block 782: detect; blocks [783,911): wprep
__global__ __launch_bounds__(256) void prep_kernel(int* __restrict__ cnt,
                                                   const int* __restrict__ eit,
                                                   const int* __restrict__ eil,
                                                   int* __restrict__ flags,
                                                   const float* __restrict__ W1,
                                                   bf16_t* __restrict__ wlay,
                                                   bf16_t* __restrict__ xw,
                                                   bf16_t* __restrict__ zb) {
    int bid = blockIdx.x;
    if (bid < ZERO_BLKS) {
        int i = bid * 256 + threadIdx.x;
        if (i < 2 * N_NODES) cnt[i] = 0;
    } else if (bid == ZERO_BLKS) {
        if (threadIdx.x < 128) {
            int lane = threadIdx.x & 63;
            const int* p = (threadIdx.x < 64) ? eit : eil;
            int s = (p[2 * lane + 1] != 0) ? 1 : 0;
            #pragma unroll
            for (int off = 1; off < 64; off <<= 1) s += __shfl_xor(s, off, 64);
            if (lane == 0) flags[(threadIdx.x < 64) ? 0 : 1] = (s == 0) ? 1 : 0;
        }
    } else {
        int w = bid - ZERO_BLKS - 1;               // 0..127
        int t = w * 256 + threadIdx.x;             // 0..32767
        if (w == 0) {
            xw[(size_t)N_NODES * HDIM + threadIdx.x] = (bf16_t)0.f;  // sentinel row
            zb[(size_t)N_NODES * HDIM + threadIdx.x] = (bf16_t)0.f;  // sentinel row
        }
        int j = t & 7, lane = (t >> 3) & 63, kk = (t >> 9) & 3, nt = t >> 11;
        int m = lane & 15, q = lane >> 4;
        int k = kk * 32 + q * 8 + j;
        int n = nt * 16 + m;
        wlay[t] = (bf16_t)W1[k * HDIM + n];
    }
}

// ---------------- gemm body: 16 rows x 256 cols per wave, row-norm fused ----------------
__device__ __forceinline__ void gemm_body(int w, int lane, const float* __restrict__ x,
                                          const bf16_t* __restrict__ wlay,
                                          bf16_t* __restrict__ xw) {
    if (w >= N_NODES / 16) return;                 // 6250 waves exactly
    int m = lane & 15, q = lane >> 4;
    int r0 = w * 16;
    int row = r0 + m;
    const float4* xr = (const float4*)(x + (size_t)row * F_INC);
    float4 u[8];
    #pragma unroll
    for (int kk = 0; kk < 4; kk++) {
        u[2 * kk]     = xr[kk * 8 + q * 2];
        u[2 * kk + 1] = xr[kk * 8 + q * 2 + 1];
    }
    float ss = 0.f;
    #pragma unroll
    for (int j = 0; j < 8; j++)
        ss += u[j].x * u[j].x + u[j].y * u[j].y + u[j].z * u[j].z + u[j].w * u[j].w;
    ss += __shfl_xor(ss, 16, 64);
    ss += __shfl_xor(ss, 32, 64);
    float rv = 1.0f / fmaxf(sqrtf(ss), 1e-12f);
    bf16x8 a[4];
    #pragma unroll
    for (int kk = 0; kk < 4; kk++) {
        float4 p0 = u[2 * kk], p1 = u[2 * kk + 1];
        a[kk][0] = (bf16_t)(p0.x * rv); a[kk][1] = (bf16_t)(p0.y * rv);
        a[kk][2] = (bf16_t)(p0.z * rv); a[kk][3] = (bf16_t)(p0.w * rv);
        a[kk][4] = (bf16_t)(p1.x * rv); a[kk][5] = (bf16_t)(p1.y * rv);
        a[kk][6] = (bf16_t)(p1.z * rv); a[kk][7] = (bf16_t)(p1.w * rv);
    }
    const bf16x8* wl = (const bf16x8*)wlay;
    #pragma unroll
    for (int nt = 0; nt < 16; nt++) {
        f32x4 c = {0.f, 0.f, 0.f, 0.f};
        c = __builtin_amdgcn_mfma_f32_16x16x32_bf16(a[0], wl[(nt * 4 + 0) * 64 + lane], c, 0, 0, 0);
        c = __builtin_amdgcn_mfma_f32_16x16x32_bf16(a[1], wl[(nt * 4 + 1) * 64 + lane], c, 0, 0, 0);
        c = __builtin_amdgcn_mfma_f32_16x16x32_bf16(a[2], wl[(nt * 4 + 2) * 64 + lane], c, 0, 0, 0);
        c = __builtin_amdgcn_mfma_f32_16x16x32_bf16(a[3], wl[(nt * 4 + 3) * 64 + lane], c, 0, 0, 0);
        #pragma unroll
        for (int i = 0; i < 4; i++) {
            xw[(size_t)(r0 + q * 4 + i) * HDIM + nt * 16 + m] = (bf16_t)c[i];
        }
    }
}

// ---------------- ELL builders: paired (src,eid) for top; src-only for last -------------
__device__ __forceinline__ void fill2_body(int e, const int* __restrict__ ei,
                                           const int* __restrict__ flag,
                                           int* __restrict__ cnt, int* __restrict__ ell2) {
    if (e >= NEDGE) return;
    int f = *flag;
    int src = ei[e << f];
    int dst = ei[(NEDGE + e) << f];
    int slot = atomicAdd(&cnt[dst], 1);
    if (slot < ELL_CAP) {
        int2 pr; pr.x = src; pr.y = e;
        ((int2*)ell2)[(size_t)dst * ELL_CAP + slot] = pr;
    }
}

__device__ __forceinline__ void fill_body(int e, const int* __restrict__ ei,
                                          const int* __restrict__ flag,
                                          int* __restrict__ cnt, int* __restrict__ ell) {
    if (e >= NEDGE) return;
    int f = *flag;
    int src = ei[e << f];
    int dst = ei[(NEDGE + e) << f];
    int slot = atomicAdd(&cnt[dst], 1);
    if (slot < ELL_CAP) ell[dst * ELL_CAP + slot] = src;
}

// ---------------- FUSED-A: gemm + fill2(top) (independent work, one dispatch) -----------
__global__ __launch_bounds__(256) void gemm_fill_kernel(const float* __restrict__ x,
                                                        const bf16_t* __restrict__ wlay,
                                                        bf16_t* __restrict__ xw,
                                                        const int* __restrict__ ei,
                                                        const int* __restrict__ flag,
                                                        int* __restrict__ cnt,
                                                        int* __restrict__ ell2) {
    if (blockIdx.x < GEMM_BLKS) {
        gemm_body(blockIdx.x * 4 + (threadIdx.x >> 6), threadIdx.x & 63, x, wlay, xw);
    } else {
        fill2_body((blockIdx.x - GEMM_BLKS) * 256 + threadIdx.x, ei, flag, cnt, ell2);
    }
}

// ---------------- dinv = rsqrt(deg+1), sentinel slot, pad ELL rows to mult of 8 ---------
__global__ void dinvpad_kernel(const int* __restrict__ cnt, float* __restrict__ dinv,
                               int* __restrict__ ell, int paired) {
    int i = blockIdx.x * 256 + threadIdx.x;
    if (i >= N_NODES) {
        if (i == N_NODES) dinv[N_NODES] = 0.f;     // sentinel: zero weight
        return;
    }
    int c = cnt[i];
    dinv[i] = rsqrtf((float)c + 1.0f);
    int deg = (c > ELL_CAP) ? ELL_CAP : c;
    int r8 = (deg + 7) & ~7;
    if (paired) {
        int2 pr; pr.x = N_NODES; pr.y = -1;
        for (int s = deg; s < r8; s++) ((int2*)ell)[(size_t)i * ELL_CAP + s] = pr;
    } else {
        for (int s = deg; s < r8; s++) ell[i * ELL_CAP + s] = N_NODES;
    }
}

// ---------------- gather conv body: 8 src rows per iteration, sentinel-padded -----------
// out[i] = dinv[i] * ( sum_e dinv[src_e]*xw[src_e] + dinv[i]*xw[i] ) + b1
template<bool PAIRED>
__device__ __forceinline__ void gather_body(int i, int lane, const int* __restrict__ ell,
                                            const int* __restrict__ cnt,
                                            const float* __restrict__ dinv,
                                            const bf16_t* __restrict__ xw,
                                            const float* __restrict__ b1,
                                            float* __restrict__ out,
                                            bf16_t* __restrict__ zb) {
    float di = dinv[i];
    const bf16x4* xws = (const bf16x4*)xw;         // row r at index r*64 + lane
    bf16x4 sv = xws[(size_t)i * 64 + lane];
    float acc0 = di * (float)sv.x;
    float acc1 = di * (float)sv.y;
    float acc2 = di * (float)sv.z;
    float acc3 = di * (float)sv.w;
    int deg = cnt[i];
    if (deg > ELL_CAP) deg = ELL_CAP;
    int nit = (deg + 7) >> 3;                      // padded with sentinel to mult of 8
    for (int b = 0; b < nit; b++) {
        int s0, s1, s2, s3, s4, s5, s6, s7;
        if (PAIRED) {
            const i32x4* e8 = (const i32x4*)ell + (size_t)i * (ELL_CAP / 2) + 4 * b;
            i32x4 A = __builtin_nontemporal_load(e8);
            i32x4 B = __builtin_nontemporal_load(e8 + 1);
            i32x4 C = __builtin_nontemporal_load(e8 + 2);
            i32x4 D = __builtin_nontemporal_load(e8 + 3);
            s0 = A[0]; s1 = A[2]; s2 = B[0]; s3 = B[2];
            s4 = C[0]; s5 = C[2]; s6 = D[0]; s7 = D[2];
        } else {
            const i32x4* el4 = (const i32x4*)(ell + (size_t)i * ELL_CAP) + 2 * b;
            i32x4 A = __builtin_nontemporal_load(el4);
            i32x4 B = __builtin_nontemporal_load(el4 + 1);
            s0 = A[0]; s1 = A[1]; s2 = A[2]; s3 = A[3];
            s4 = B[0]; s5 = B[1]; s6 = B[2]; s7 = B[3];
        }
        // 8 independent row loads in flight before the FMAs
        bf16x4 v0 = xws[(size_t)s0 * 64 + lane];
        bf16x4 v1 = xws[(size_t)s1 * 64 + lane];
        bf16x4 v2 = xws[(size_t)s2 * 64 + lane];
        bf16x4 v3 = xws[(size_t)s3 * 64 + lane];
        bf16x4 v4 = xws[(size_t)s4 * 64 + lane];
        bf16x4 v5 = xws[(size_t)s5 * 64 + lane];
        bf16x4 v6 = xws[(size_t)s6 * 64 + lane];
        bf16x4 v7 = xws[(size_t)s7 * 64 + lane];
        float d0 = dinv[s0], d1 = dinv[s1], d2 = dinv[s2], d3 = dinv[s3];
        float d4 = dinv[s4], d5 = dinv[s5], d6 = dinv[s6], d7 = dinv[s7];
        acc0 += d0 * (float)v0.x + d1 * (float)v1.x + d2 * (float)v2.x + d3 * (float)v3.x
              + d4 * (float)v4.x + d5 * (float)v5.x + d6 * (float)v6.x + d7 * (float)v7.x;
        acc1 += d0 * (float)v0.y + d1 * (float)v1.y + d2 * (float)v2.y + d3 * (float)v3.y
              + d4 * (float)v4.y + d5 * (float)v5.y + d6 * (float)v6.y + d7 * (float)v7.y;
        acc2 += d0 * (float)v0.z + d1 * (float)v1.z + d2 * (float)v2.z + d3 * (float)v3.z
              + d4 * (float)v4.z + d5 * (float)v5.z + d6 * (float)v6.z + d7 * (float)v7.z;
        acc3 += d0 * (float)v0.w + d1 * (float)v1.w + d2 * (float)v2.w + d3 * (float)v3.w
              + d4 * (float)v4.w + d5 * (float)v5.w + d6 * (float)v6.w + d7 * (float)v7.w;
    }
    float4 bv = ((const float4*)b1)[lane];
    f32x4 o;
    o[0] = di * acc0 + bv.x;
    o[1] = di * acc1 + bv.y;
    o[2] = di * acc2 + bv.z;
    o[3] = di * acc3 + bv.w;
    // streaming store (nontemporal): reduce cache churn for the gather hot set
    __builtin_nontemporal_store(o, (f32x4*)out + (size_t)i * 64 + lane);
    if (zb) {
        bf16x4 zo;
        zo.x = (bf16_t)o[0]; zo.y = (bf16_t)o[1]; zo.z = (bf16_t)o[2]; zo.w = (bf16_t)o[3];
        ((bf16x4*)zb)[(size_t)i * 64 + lane] = zo;                           // re-read: cached
    }
}

// ---------------- FUSED-B: gather(top) + fill_ell(last) -------------------------------
__global__ __launch_bounds__(256) void gather_fill_kernel(const int* __restrict__ ell2,
                                                          const int* __restrict__ cnt,
                                                          const float* __restrict__ dinv,
                                                          const bf16_t* __restrict__ xw,
                                                          const float* __restrict__ b1,
                                                          float* __restrict__ out,
                                                          bf16_t* __restrict__ zb,
                                                          const int* __restrict__ ei_l,
                                                          const int* __restrict__ flag_l,
                                                          int* __restrict__ cnt_l,
                                                          int* __restrict__ ell_l) {
    if (blockIdx.x < FILL_BLKS) {
        fill_body(blockIdx.x * 256 + threadIdx.x, ei_l, flag_l, cnt_l, ell_l);
    } else {
        gather_body<true>((blockIdx.x - FILL_BLKS) * 4 + (threadIdx.x >> 6), threadIdx.x & 63,
                          ell2, cnt, dinv, xw, b1, out, zb);
    }
}

// ---------------- aedge (dst-major, unroll 2): dst row loaded once per node -------------
// wave = one dst node; 4x 16-lane groups, each handles 2 edge slots per iteration
__device__ __forceinline__ void aedge_body(int i, int lane, const int* __restrict__ ell2,
                                           const int* __restrict__ cnt,
                                           const bf16_t* __restrict__ zb,
                                           float* __restrict__ aedge) {
    int sub = lane & 15, g = lane >> 4;
    const bf16x8* z8 = (const bf16x8*)zb;          // row r: 32 bf16x8 at r*32
    bf16x8 d0 = z8[(size_t)i * 32 + sub * 2];      // dst row: once per node
    bf16x8 d1 = z8[(size_t)i * 32 + sub * 2 + 1];
    int deg = cnt[i];
    if (deg > ELL_CAP) deg = ELL_CAP;
    int nit = (deg + 7) >> 3;                      // ELL padded to mult of 8
    const i32x2* pr = (const i32x2*)ell2 + (size_t)i * ELL_CAP;
    for (int b = 0; b < nit; b++) {
        i32x2 pA = __builtin_nontemporal_load(pr + b * 8 + g);
        i32x2 pB = __builtin_nontemporal_load(pr + b * 8 + 4 + g);
        int sA = pA[0], sB = pB[0];
        bf16x8 a0 = z8[(size_t)sA * 32 + sub * 2];
        bf16x8 a1 = z8[(size_t)sA * 32 + sub * 2 + 1];
        bf16x8 c0 = z8[(size_t)sB * 32 + sub * 2];
        bf16x8 c1 = z8[(size_t)sB * 32 + sub * 2 + 1];
        float p = 0.f, q = 0.f;
        #pragma unroll
        for (int j = 0; j < 8; j++) {
            p += (float)a0[j] * (float)d0[j] + (float)a1[j] * (float)d1[j];
            q += (float)c0[j] * (float)d0[j] + (float)c1[j] * (float)d1[j];
        }
        #pragma unroll
        for (int off = 1; off < 16; off <<= 1) {
            p += __shfl_xor(p, off, 64);
            q += __shfl_xor(q, off, 64);
        }
        if (sub == 0) {
            if (pA[1] >= 0)
                __builtin_nontemporal_store(1.0f / (1.0f + __expf(-p)), &aedge[pA[1]]);
            if (pB[1] >= 0)
                __builtin_nontemporal_store(1.0f / (1.0f + __expf(-q)), &aedge[pB[1]]);
        }
    }
}

// ---------------- FUSED-C: gather(last) + aedge(top), block-parity interleaved ----------
__global__ __launch_bounds__(256) void fused_last_kernel(const int* __restrict__ ell_l,
                                                         const int* __restrict__ cnt_l,
                                                         const float* __restrict__ dinv_l,
                                                         const bf16_t* __restrict__ xw,
                                                         const float* __restrict__ b1,
                                                         float* __restrict__ out1,
                                                         const int* __restrict__ ell2_t,
                                                         const int* __restrict__ cnt_t,
                                                         const bf16_t* __restrict__ zb,
                                                         float* __restrict__ aedge) {
    int lane = threadIdx.x & 63;
    int node = (blockIdx.x >> 1) * 4 + (threadIdx.x >> 6);
    if (blockIdx.x & 1) {
        aedge_body(node, lane, ell2_t, cnt_t, zb, aedge);
    } else {
        gather_body<false>(node, lane, ell_l, cnt_l, dinv_l, xw, b1, out1, (bf16_t*)0);
    }
}

extern "C" void kernel_launch(void* const* d_in, const int* in_sizes, int n_in,
                              void* d_out, int out_size, void* d_ws, size_t ws_size,
                              hipStream_t stream) {
    const float* x       = (const float*)d_in[0];
    const int*   ei_top  = (const int*)d_in[1];
    const int*   ei_last = (const int*)d_in[2];
    const float* W1      = (const float*)d_in[3];
    const float* b1      = (const float*)d_in[4];
    float* out = (float*)d_out;

    char* ws = (char*)d_ws;
    bf16_t* xw     = (bf16_t*)(ws);                  //  51,200,512 B (+sentinel row)
    bf16_t* zb     = (bf16_t*)(ws + 51201024);       //  51,200,512 B (+sentinel row)
    int*    ell2t  = (int*)  (ws + 102402048);       //  38,400,000 B (src,eid pairs, top)
    int*    ell_l  = (int*)  (ws + 140802048);       //  19,200,000 B (src only, last)
    float*  dinv_t = (float*)(ws + 160002048);       //     400,064 B (N+1 floats)
    float*  dinv_l = (float*)(ws + 160402112);       //     400,064 B
    int*    cnt_t  = (int*)  (ws + 160802176);       //     400,000 B
    int*    cnt_l  = (int*)  (ws + 161202176);       //     400,000 B (contiguous w/ cnt_t)
    bf16_t* wlay   = (bf16_t*)(ws + 161602176);      //      65,536 B
    int*    flags  = (int*)  (ws + 161667712);       //          64 B -> 161,667,776 total

    // zero counters + detect layout + pack W1 (one dispatch)
    prep_kernel<<<ZERO_BLKS + 1 + 128, 256, 0, stream>>>(cnt_t, ei_top, ei_last, flags,
                                                         W1, wlay, xw, zb);
    // gemm + fill2(top) fused (independent work)
    gemm_fill_kernel<<<GEMM_BLKS + FILL_BLKS, 256, 0, stream>>>(x, wlay, xw,
                                                                ei_top, flags, cnt_t, ell2t);
    dinvpad_kernel<<<(N_NODES + 256) / 256 + 1, 256, 0, stream>>>(cnt_t, dinv_t, ell2t, 1);
    // gather(top) -> out0 fp32 + zb bf16, fused with fill_ell(last)
    gather_fill_kernel<<<FILL_BLKS + GATHER_BLKS, 256, 0, stream>>>(
        ell2t, cnt_t, dinv_t, xw, b1, out, zb, ei_last, flags + 1, cnt_l, ell_l);
    dinvpad_kernel<<<(N_NODES + 256) / 256 + 1, 256, 0, stream>>>(cnt_l, dinv_l, ell_l, 0);
    // gather(last) + aedge(top): block-parity interleaved, disjoint hot arrays
    fused_last_kernel<<<2 * GATHER_BLKS, 256, 0, stream>>>(
        ell_l, cnt_l, dinv_l, xw, b1, out + (size_t)N_NODES * HDIM,
        ell2t, cnt_t, zb, out + (size_t)2 * N_NODES * HDIM);
}

// Round 9
// 643.110 us; speedup vs baseline: 1.1019x; 1.0537x over previous
//
#include <hip/hip_runtime.h>
#include <hip/hip_bf16.h>

typedef __bf16 bf16_t;
typedef __bf16 bf16x4 __attribute__((ext_vector_type(4)));
typedef __bf16 bf16x8 __attribute__((ext_vector_type(8)));
typedef float  f32x4  __attribute__((ext_vector_type(4)));

#define N_NODES 100000
#define F_INC   128
#define HDIM    256
#define NEDGE   1000000
#define ELL_CAP 48
#define GATHER_BLKS (N_NODES / 4)             // 25000
#define GEMM_BLKS   ((N_NODES / 16 + 3) / 4)  // 1563
#define FILL_BLKS   ((NEDGE + 255) / 256)     // 3907
#define ZERO_BLKS   ((2 * N_NODES + 255) / 256) // 782

// ---------------- PREP: zero counters + detect int32/64 + pre-pack W1 -------------------
// blocks [0,782): zero cnt_t/cnt_l; block 782: detect; blocks [783,911): wprep
__global__ __launch_bounds__(256) void prep_kernel(int* __restrict__ cnt,
                                                   const int* __restrict__ eit,
                                                   const int* __restrict__ eil,
                                                   int* __restrict__ flags,
                                                   const float* __restrict__ W1,
                                                   bf16_t* __restrict__ wlay,
                                                   bf16_t* __restrict__ xw,
                                                   bf16_t* __restrict__ zb) {
    int bid = blockIdx.x;
    if (bid < ZERO_BLKS) {
        int i = bid * 256 + threadIdx.x;
        if (i < 2 * N_NODES) cnt[i] = 0;
    } else if (bid == ZERO_BLKS) {
        if (threadIdx.x < 128) {
            int lane = threadIdx.x & 63;
            const int* p = (threadIdx.x < 64) ? eit : eil;
            int s = (p[2 * lane + 1] != 0) ? 1 : 0;
            #pragma unroll
            for (int off = 1; off < 64; off <<= 1) s += __shfl_xor(s, off, 64);
            if (lane == 0) flags[(threadIdx.x < 64) ? 0 : 1] = (s == 0) ? 1 : 0;
        }
    } else {
        int w = bid - ZERO_BLKS - 1;               // 0..127
        int t = w * 256 + threadIdx.x;             // 0..32767
        if (w == 0) {
            xw[(size_t)N_NODES * HDIM + threadIdx.x] = (bf16_t)0.f;  // sentinel row
            zb[(size_t)N_NODES * HDIM + threadIdx.x] = (bf16_t)0.f;  // sentinel row
        }
        int j = t & 7, lane = (t >> 3) & 63, kk = (t >> 9) & 3, nt = t >> 11;
        int m = lane & 15, q = lane >> 4;
        int k = kk * 32 + q * 8 + j;
        int n = nt * 16 + m;
        wlay[t] = (bf16_t)W1[k * HDIM + n];
    }
}

// ---------------- gemm body: 16 rows x 256 cols per wave, row-norm fused ----------------
__device__ __forceinline__ void gemm_body(int w, int lane, const float* __restrict__ x,
                                          const bf16_t* __restrict__ wlay,
                                          bf16_t* __restrict__ xw) {
    if (w >= N_NODES / 16) return;                 // 6250 waves exactly
    int m = lane & 15, q = lane >> 4;
    int r0 = w * 16;
    int row = r0 + m;
    const float4* xr = (const float4*)(x + (size_t)row * F_INC);
    float4 u[8];
    #pragma unroll
    for (int kk = 0; kk < 4; kk++) {
        u[2 * kk]     = xr[kk * 8 + q * 2];
        u[2 * kk + 1] = xr[kk * 8 + q * 2 + 1];
    }
    float ss = 0.f;
    #pragma unroll
    for (int j = 0; j < 8; j++)
        ss += u[j].x * u[j].x + u[j].y * u[j].y + u[j].z * u[j].z + u[j].w * u[j].w;
    ss += __shfl_xor(ss, 16, 64);
    ss += __shfl_xor(ss, 32, 64);
    float rv = 1.0f / fmaxf(sqrtf(ss), 1e-12f);
    bf16x8 a[4];
    #pragma unroll
    for (int kk = 0; kk < 4; kk++) {
        float4 p0 = u[2 * kk], p1 = u[2 * kk + 1];
        a[kk][0] = (bf16_t)(p0.x * rv); a[kk][1] = (bf16_t)(p0.y * rv);
        a[kk][2] = (bf16_t)(p0.z * rv); a[kk][3] = (bf16_t)(p0.w * rv);
        a[kk][4] = (bf16_t)(p1.x * rv); a[kk][5] = (bf16_t)(p1.y * rv);
        a[kk][6] = (bf16_t)(p1.z * rv); a[kk][7] = (bf16_t)(p1.w * rv);
    }
    const bf16x8* wl = (const bf16x8*)wlay;
    #pragma unroll
    for (int nt = 0; nt < 16; nt++) {
        f32x4 c = {0.f, 0.f, 0.f, 0.f};
        c = __builtin_amdgcn_mfma_f32_16x16x32_bf16(a[0], wl[(nt * 4 + 0) * 64 + lane], c, 0, 0, 0);
        c = __builtin_amdgcn_mfma_f32_16x16x32_bf16(a[1], wl[(nt * 4 + 1) * 64 + lane], c, 0, 0, 0);
        c = __builtin_amdgcn_mfma_f32_16x16x32_bf16(a[2], wl[(nt * 4 + 2) * 64 + lane], c, 0, 0, 0);
        c = __builtin_amdgcn_mfma_f32_16x16x32_bf16(a[3], wl[(nt * 4 + 3) * 64 + lane], c, 0, 0, 0);
        #pragma unroll
        for (int i = 0; i < 4; i++) {
            xw[(size_t)(r0 + q * 4 + i) * HDIM + nt * 16 + m] = (bf16_t)c[i];
        }
    }
}

// ---------------- ELL builders: paired (src,eid) for top; src-only for last -------------
__device__ __forceinline__ void fill2_body(int e, const int* __restrict__ ei,
                                           const int* __restrict__ flag,
                                           int* __restrict__ cnt, int* __restrict__ ell2) {
    if (e >= NEDGE) return;
    int f = *flag;
    int src = ei[e << f];
    int dst = ei[(NEDGE + e) << f];
    int slot = atomicAdd(&cnt[dst], 1);
    if (slot < ELL_CAP) {
        int2 pr; pr.x = src; pr.y = e;
        ((int2*)ell2)[(size_t)dst * ELL_CAP + slot] = pr;
    }
}

__device__ __forceinline__ void fill_body(int e, const int* __restrict__ ei,
                                          const int* __restrict__ flag,
                                          int* __restrict__ cnt, int* __restrict__ ell) {
    if (e >= NEDGE) return;
    int f = *flag;
    int src = ei[e << f];
    int dst = ei[(NEDGE + e) << f];
    int slot = atomicAdd(&cnt[dst], 1);
    if (slot < ELL_CAP) ell[dst * ELL_CAP + slot] = src;
}

// ---------------- FUSED-A: gemm + fill2(top) (independent work, one dispatch) -----------
__global__ __launch_bounds__(256) void gemm_fill_kernel(const float* __restrict__ x,
                                                        const bf16_t* __restrict__ wlay,
                                                        bf16_t* __restrict__ xw,
                                                        const int* __restrict__ ei,
                                                        const int* __restrict__ flag,
                                                        int* __restrict__ cnt,
                                                        int* __restrict__ ell2) {
    if (blockIdx.x < GEMM_BLKS) {
        gemm_body(blockIdx.x * 4 + (threadIdx.x >> 6), threadIdx.x & 63, x, wlay, xw);
    } else {
        fill2_body((blockIdx.x - GEMM_BLKS) * 256 + threadIdx.x, ei, flag, cnt, ell2);
    }
}

// ---------------- dinv = rsqrt(deg+1), sentinel slot, pad ELL rows to mult of 4 ---------
__global__ void dinvpad_kernel(const int* __restrict__ cnt, float* __restrict__ dinv,
                               int* __restrict__ ell, int paired) {
    int i = blockIdx.x * 256 + threadIdx.x;
    if (i >= N_NODES) {
        if (i == N_NODES) dinv[N_NODES] = 0.f;     // sentinel: zero weight
        return;
    }
    int c = cnt[i];
    dinv[i] = rsqrtf((float)c + 1.0f);
    int deg = (c > ELL_CAP) ? ELL_CAP : c;
    int r4 = (deg + 3) & ~3;
    if (paired) {
        int2 pr; pr.x = N_NODES; pr.y = -1;
        for (int s = deg; s < r4; s++) ((int2*)ell)[(size_t)i * ELL_CAP + s] = pr;
    } else {
        for (int s = deg; s < r4; s++) ell[i * ELL_CAP + s] = N_NODES;
    }
}

// ---------------- gather conv body: sentinel-padded, index-chunk software pipeline ------
// out[i] = dinv[i] * ( sum_e dinv[src_e]*xw[src_e] + dinv[i]*xw[i] ) + b1
template<bool PAIRED>
__device__ __forceinline__ void gather_body(int i, int lane, const int* __restrict__ ell,
                                            const int* __restrict__ cnt,
                                            const float* __restrict__ dinv,
                                            const bf16_t* __restrict__ xw,
                                            const float* __restrict__ b1,
                                            float* __restrict__ out,
                                            bf16_t* __restrict__ zb) {
    float di = dinv[i];
    const bf16x4* xws = (const bf16x4*)xw;         // row r at index r*64 + lane
    bf16x4 sv = xws[(size_t)i * 64 + lane];
    float acc0 = di * (float)sv.x;
    float acc1 = di * (float)sv.y;
    float acc2 = di * (float)sv.z;
    float acc3 = di * (float)sv.w;
    int deg = cnt[i];
    if (deg > ELL_CAP) deg = ELL_CAP;
    int nit = (deg + 3) >> 2;                      // padded with sentinel to mult of 4
    int4 sa, sb;                                   // current chunk (sa.x/.z,sb.x/.z if paired)
    if (PAIRED) {
        const int4* e8 = (const int4*)ell + (size_t)i * (ELL_CAP / 2);
        sa = e8[0]; sb = e8[1];
        for (int b = 0; b < nit; b++) {
            int bn = (b + 1 < nit) ? (b + 1) : b;
            int4 na = e8[2 * bn], nb = e8[2 * bn + 1];
            int s0 = sa.x, s1 = sa.z, s2 = sb.x, s3 = sb.z;
            float d0 = dinv[s0], d1 = dinv[s1], d2 = dinv[s2], d3 = dinv[s3];
            bf16x4 v0 = xws[(size_t)s0 * 64 + lane];
            bf16x4 v1 = xws[(size_t)s1 * 64 + lane];
            bf16x4 v2 = xws[(size_t)s2 * 64 + lane];
            bf16x4 v3 = xws[(size_t)s3 * 64 + lane];
            acc0 += d0 * (float)v0.x + d1 * (float)v1.x + d2 * (float)v2.x + d3 * (float)v3.x;
            acc1 += d0 * (float)v0.y + d1 * (float)v1.y + d2 * (float)v2.y + d3 * (float)v3.y;
            acc2 += d0 * (float)v0.z + d1 * (float)v1.z + d2 * (float)v2.z + d3 * (float)v3.z;
            acc3 += d0 * (float)v0.w + d1 * (float)v1.w + d2 * (float)v2.w + d3 * (float)v3.w;
            sa = na; sb = nb;
        }
    } else {
        const int4* el4 = (const int4*)(ell + (size_t)i * ELL_CAP);
        sa = el4[0];
        for (int b = 0; b < nit; b++) {
            int bn = (b + 1 < nit) ? (b + 1) : b;
            int4 na = el4[bn];
            int s0 = sa.x, s1 = sa.y, s2 = sa.z, s3 = sa.w;
            float d0 = dinv[s0], d1 = dinv[s1], d2 = dinv[s2], d3 = dinv[s3];
            bf16x4 v0 = xws[(size_t)s0 * 64 + lane];
            bf16x4 v1 = xws[(size_t)s1 * 64 + lane];
            bf16x4 v2 = xws[(size_t)s2 * 64 + lane];
            bf16x4 v3 = xws[(size_t)s3 * 64 + lane];
            acc0 += d0 * (float)v0.x + d1 * (float)v1.x + d2 * (float)v2.x + d3 * (float)v3.x;
            acc1 += d0 * (float)v0.y + d1 * (float)v1.y + d2 * (float)v2.y + d3 * (float)v3.y;
            acc2 += d0 * (float)v0.z + d1 * (float)v1.z + d2 * (float)v2.z + d3 * (float)v3.z;
            acc3 += d0 * (float)v0.w + d1 * (float)v1.w + d2 * (float)v2.w + d3 * (float)v3.w;
            sa = na;
        }
    }
    float4 bv = ((const float4*)b1)[lane];
    f32x4 o;
    o[0] = di * acc0 + bv.x;
    o[1] = di * acc1 + bv.y;
    o[2] = di * acc2 + bv.z;
    o[3] = di * acc3 + bv.w;
    // streaming store (nontemporal): keep L2/L3 for the gather hot set
    __builtin_nontemporal_store(o, (f32x4*)out + (size_t)i * 64 + lane);
    if (zb) {
        bf16x4 zo;
        zo.x = (bf16_t)o[0]; zo.y = (bf16_t)o[1]; zo.z = (bf16_t)o[2]; zo.w = (bf16_t)o[3];
        ((bf16x4*)zb)[(size_t)i * 64 + lane] = zo;                           // re-read: cached
    }
}

// ---------------- FUSED-B: gather(top) + fill_ell(last) -------------------------------
__global__ __launch_bounds__(256) void gather_fill_kernel(const int* __restrict__ ell2,
                                                          const int* __restrict__ cnt,
                                                          const float* __restrict__ dinv,
                                                          const bf16_t* __restrict__ xw,
                                                          const float* __restrict__ b1,
                                                          float* __restrict__ out,
                                                          bf16_t* __restrict__ zb,
                                                          const int* __restrict__ ei_l,
                                                          const int* __restrict__ flag_l,
                                                          int* __restrict__ cnt_l,
                                                          int* __restrict__ ell_l) {
    if (blockIdx.x < FILL_BLKS) {
        fill_body(blockIdx.x * 256 + threadIdx.x, ei_l, flag_l, cnt_l, ell_l);
    } else {
        gather_body<true>((blockIdx.x - FILL_BLKS) * 4 + (threadIdx.x >> 6), threadIdx.x & 63,
                          ell2, cnt, dinv, xw, b1, out, zb);
    }
}

// ---------------- aedge (dst-major): dst row loaded once per node ------------------------
// wave = one dst node; 4x 16-lane groups each handle one edge slot per iteration
__device__ __forceinline__ void aedge_dst_body(int i, int lane, const int* __restrict__ ell2,
                                               const int* __restrict__ cnt,
                                               const bf16_t* __restrict__ zb,
                                               float* __restrict__ aedge) {
    int sub = lane & 15, g = lane >> 4;
    const bf16x8* z8 = (const bf16x8*)zb;          // row r: 32 bf16x8 at r*32
    bf16x8 d0 = z8[(size_t)i * 32 + sub * 2];      // dst row: once per node
    bf16x8 d1 = z8[(size_t)i * 32 + sub * 2 + 1];
    int deg = cnt[i];
    if (deg > ELL_CAP) deg = ELL_CAP;
    int nit = (deg + 3) >> 2;
    if (nit == 0) return;
    const int2* pr = (const int2*)ell2 + (size_t)i * ELL_CAP;
    int2 pe = pr[g];
    for (int b = 0; b < nit; b++) {
        int bn = (b + 1 < nit) ? (b + 1) : b;
        int2 pn = pr[bn * 4 + g];
        int src = pe.x, eid = pe.y;
        bf16x8 a0 = z8[(size_t)src * 32 + sub * 2];
        bf16x8 a1 = z8[(size_t)src * 32 + sub * 2 + 1];
        float p = 0.f;
        #pragma unroll
        for (int j = 0; j < 8; j++)
            p += (float)a0[j] * (float)d0[j] + (float)a1[j] * (float)d1[j];
        #pragma unroll
        for (int off = 1; off < 16; off <<= 1) p += __shfl_xor(p, off, 64);
        if (sub == 0 && eid >= 0)
            __builtin_nontemporal_store(1.0f / (1.0f + __expf(-p)), &aedge[eid]);
        pe = pn;
    }
}

// ---------------- FUSED-C: gather(last) + aedge-dst(top), parity-interleaved ------------
__global__ __launch_bounds__(256) void fused_last_kernel(const int* __restrict__ ell_l,
                                                         const int* __restrict__ cnt_l,
                                                         const float* __restrict__ dinv_l,
                                                         const bf16_t* __restrict__ xw,
                                                         const float* __restrict__ b1,
                                                         float* __restrict__ out1,
                                                         const int* __restrict__ ell2_t,
                                                         const int* __restrict__ cnt_t,
                                                         const bf16_t* __restrict__ zb,
                                                         float* __restrict__ aedge) {
    int lane = threadIdx.x & 63;
    int node = (blockIdx.x >> 1) * 4 + (threadIdx.x >> 6);
    if (blockIdx.x & 1) {
        aedge_dst_body(node, lane, ell2_t, cnt_t, zb, aedge);
    } else {
        gather_body<false>(node, lane, ell_l, cnt_l, dinv_l, xw, b1, out1, (bf16_t*)0);
    }
}

extern "C" void kernel_launch(void* const* d_in, const int* in_sizes, int n_in,
                              void* d_out, int out_size, void* d_ws, size_t ws_size,
                              hipStream_t stream) {
    const float* x       = (const float*)d_in[0];
    const int*   ei_top  = (const int*)d_in[1];
    const int*   ei_last = (const int*)d_in[2];
    const float* W1      = (const float*)d_in[3];
    const float* b1      = (const float*)d_in[4];
    float* out = (float*)d_out;

    char* ws = (char*)d_ws;
    bf16_t* xw     = (bf16_t*)(ws);                  //  51,200,512 B (+sentinel row)
    bf16_t* zb     = (bf16_t*)(ws + 51201024);       //  51,200,512 B (+sentinel row)
    int*    ell2t  = (int*)  (ws + 102402048);       //  38,400,000 B (src,eid pairs, top)
    int*    ell_l  = (int*)  (ws + 140802048);       //  19,200,000 B (src only, last)
    float*  dinv_t = (float*)(ws + 160002048);       //     400,064 B (N+1 floats)
    float*  dinv_l = (float*)(ws + 160402112);       //     400,064 B
    int*    cnt_t  = (int*)  (ws + 160802176);       //     400,000 B
    int*    cnt_l  = (int*)  (ws + 161202176);       //     400,000 B (contiguous w/ cnt_t)
    bf16_t* wlay   = (bf16_t*)(ws + 161602176);      //      65,536 B
    int*    flags  = (int*)  (ws + 161667712);       //          64 B -> 161,667,776 total

    // zero counters + detect layout + pack W1 (one dispatch)
    prep_kernel<<<ZERO_BLKS + 1 + 128, 256, 0, stream>>>(cnt_t, ei_top, ei_last, flags,
                                                         W1, wlay, xw, zb);
    // gemm + fill2(top) fused (independent work)
    gemm_fill_kernel<<<GEMM_BLKS + FILL_BLKS, 256, 0, stream>>>(x, wlay, xw,
                                                                ei_top, flags, cnt_t, ell2t);
    dinvpad_kernel<<<(N_NODES + 256) / 256 + 1, 256, 0, stream>>>(cnt_t, dinv_t, ell2t, 1);
    // gather(top) -> out0 fp32 + zb bf16, fused with fill_ell(last)
    gather_fill_kernel<<<FILL_BLKS + GATHER_BLKS, 256, 0, stream>>>(
        ell2t, cnt_t, dinv_t, xw, b1, out, zb, ei_last, flags + 1, cnt_l, ell_l);
    dinvpad_kernel<<<(N_NODES + 256) / 256 + 1, 256, 0, stream>>>(cnt_l, dinv_l, ell_l, 0);
    // gather(last) + aedge-dst(top): parity-interleaved, disjoint hot arrays
    fused_last_kernel<<<2 * GATHER_BLKS, 256, 0, stream>>>(
        ell_l, cnt_l, dinv_l, xw, b1, out + (size_t)N_NODES * HDIM,
        ell2t, cnt_t, zb, out + (size_t)2 * N_NODES * HDIM);
}